// Round 5
// baseline (318.685 us; speedup 1.0000x reference)
//
#include <hip/hip_runtime.h>
#include <hip/hip_bf16.h>
#include <math.h>

#define B_ 1024
#define S_ 200
#define D_ 128
#define H_ 128
#define N_ 64

typedef __attribute__((ext_vector_type(8))) short short8;
typedef __attribute__((ext_vector_type(8))) __bf16 bf16x8;
typedef __attribute__((ext_vector_type(4))) float floatx4;

static __device__ __forceinline__ float bf2f(unsigned short u) {
    union { unsigned int i; float f; } v; v.i = ((unsigned int)u) << 16; return v.f;
}
static __device__ __forceinline__ unsigned short f2bf(float f) {
    union { float f; unsigned int u; } v; v.f = f;
    unsigned int u = v.u;
    return (unsigned short)((u + 0x7FFFu + ((u >> 16) & 1u)) >> 16);   // RNE
}
static __device__ __forceinline__ float ld1(const void* p, int isbf, size_t i) {
    return isbf ? bf2f(((const unsigned short*)p)[i]) : ((const float*)p)[i];
}
static __device__ __forceinline__ float fast_tanh(float x) {
    float t = __expf(2.0f * x);
    return 1.0f - 2.0f * __builtin_amdgcn_rcpf(t + 1.0f);   // err ~2e-5
}

// ---- wave-local dtype detection (no barriers; every wave computes the same flag) ----
static __device__ __forceinline__ int detect_wave_256(const void* p) {
    int lane = threadIdx.x & 63;
    uint4 w = ((const uint4*)p)[lane];          // 256 words sampled per wave
    unsigned int ws[4] = {w.x, w.y, w.z, w.w};
    int pass = 0;
#pragma unroll
    for (int k = 0; k < 4; ++k) {
        unsigned int e = (ws[k] >> 7) & 0xFF;   // exponent of lo-bf16 if data is bf16
        pass += (e == 0 || (e >= 96 && e <= 140)) ? 1 : 0;
    }
#pragma unroll
    for (int off = 32; off; off >>= 1) pass += __shfl_xor(pass, off, 64);
    return pass * 4 >= 256 * 3;
}
static __device__ __forceinline__ int detect_wave_64(const void* p) {
    int lane = threadIdx.x & 63;
    unsigned int w = ((const unsigned int*)p)[lane];   // 64 words
    unsigned int e = (w >> 7) & 0xFF;
    int pass = (e == 0 || (e >= 96 && e <= 140)) ? 1 : 0;
#pragma unroll
    for (int off = 32; off; off >>= 1) pass += __shfl_xor(pass, off, 64);
    return pass * 4 >= 64 * 3;
}
static __device__ __forceinline__ int detect_mask_u8(const void* p) {
    int lane = threadIdx.x & 63;
    uint4 w = ((const uint4*)p)[lane];          // first 1 KB of mask
    unsigned int x = (w.x | w.y | w.z | w.w) & 0xFFFFFF00u;  // nonzero high bytes => u8
    return (__ballot(x != 0) != 0ULL) ? 1 : 0;
}

// ---------------- prep: block 0 -> WeTf (fragment-swizzled); blocks 1..200 -> pbL rows ----
// WeTf layout: frag = nt*4+kks; WeTf[(frag*64+lane)*8+j] = We[kks*32+(lane>>4)*8+j][nt*16+(lane&15)]
// pbL layout (per-lane C-fragment order): float idx ((mt*8+nt)*64 + quad*16 + mrow)*4 + reg
//   = pb[s = mt*16+quad*4+reg][h = nt*16+mrow]. mt=12 entries with s>=200 are zero-filled.
__global__ __launch_bounds__(128) void prep_kernel(
    const void* __restrict__ We, const void* __restrict__ pos,
    const void* __restrict__ Wp,
    unsigned short* __restrict__ WeTf, float* __restrict__ pbL)
{
    int blk = blockIdx.x, t = threadIdx.x;
    __shared__ unsigned short T[128][136];
    __shared__ float prow[D_];
    __shared__ int fl[2];
    if (blk == 0) {
        if (t < 64) { int f = detect_wave_256(We); if (t == 0) fl[0] = f; }
        __syncthreads();
        int fWe = fl[0];
        for (int c = t; c < 2048; c += 128) {
            int d = c >> 4, h8 = (c & 15) * 8;
            short8 v;
            if (fWe) {
                v = *(const short8*)((const unsigned short*)We + d * H_ + h8);
            } else {
                const float* p = (const float*)We + d * H_ + h8;
                float4 a = ((const float4*)p)[0], b = ((const float4*)p)[1];
                v[0] = (short)f2bf(a.x); v[1] = (short)f2bf(a.y);
                v[2] = (short)f2bf(a.z); v[3] = (short)f2bf(a.w);
                v[4] = (short)f2bf(b.x); v[5] = (short)f2bf(b.y);
                v[6] = (short)f2bf(b.z); v[7] = (short)f2bf(b.w);
            }
            *(short8*)(&T[d][h8]) = v;
        }
        __syncthreads();
        for (int i = t; i < 2048; i += 128) {
            int frag = i >> 6, ln = i & 63;
            int nt = frag >> 2, kks = frag & 3;
            int h = nt * 16 + (ln & 15);
            int dbase = kks * 32 + (ln >> 4) * 8;
            short8 v;
#pragma unroll
            for (int j = 0; j < 8; ++j) v[j] = (short)T[dbase + j][h];
            *(short8*)(WeTf + (size_t)i * 8) = v;
        }
        // zero-fill pbL entries for mt=12, s_local >= 8 (s = 200..207)
        for (int i = t; i < 1024; i += 128) {
            int nt = i >> 7, j = i & 127;
            int q = 2 + (j >> 6), m = (j >> 2) & 15, r = j & 3;
            pbL[(((96 + nt) * 64 + q * 16 + m) << 2) + r] = 0.f;
        }
    } else {
        if (t < 64)       { int f = detect_wave_256(pos); if (t == 0)  fl[0] = f; }
        else if (t < 128) { int f = detect_wave_256(Wp);  if (t == 64) fl[1] = f; }
        __syncthreads();
        int fPos = fl[0], fWp = fl[1];
        int s = blk - 1, h = t;
        prow[h] = ld1(pos, fPos, (size_t)s * D_ + h);
        __syncthreads();
        float acc = 0.f;
        if (fWp) {
            const unsigned short* W = (const unsigned short*)Wp;
            for (int d = 0; d < D_; ++d) acc = fmaf(prow[d], bf2f(W[d * H_ + h]), acc);
        } else {
            const float* W = (const float*)Wp;
            for (int d = 0; d < D_; ++d) acc = fmaf(prow[d], W[d * H_ + h], acc);
        }
        int mt = s >> 4, qr = s & 15;
        int idx = (((mt * 8 + (h >> 4)) * 64 + (qr >> 2) * 16 + (h & 15)) << 2) + (qr & 3);
        pbL[idx] = acc;
    }
}

// ---------------- fused: block per b, 8 waves (wave = n-tile), NO big LDS staging -------
// A-fragments stream from global (L1/L2 merge the 8 waves' identical rows); B-fragments
// in registers; LDS only ~18 KB. No prefetch buffers: ~55 live VGPRs fits the
// launch_bounds(512,6) cap of 85 with margin -> no spill, ~3 blocks/CU.
__global__ __launch_bounds__(512, 6) void fused_kernel(
    const void* __restrict__ Xs, const void* __restrict__ Xitem,
    const void* __restrict__ maskv, const void* __restrict__ origin,
    const unsigned short* __restrict__ WeTf, const float* __restrict__ pbL,
    const void* __restrict__ zv,
    float* __restrict__ pos_loss, float* __restrict__ neg_sum,
    float* __restrict__ out)
{
    int b = blockIdx.x, t = threadIdx.x;
    int wv = t >> 6, lane = t & 63;
    int quad = lane >> 4, mrow = lane & 15;

    __shared__ __align__(16) float ubuf[4096];   // sp[8][208] | partial[32][128] | p_oo/p_ov
    __shared__ float attn[256];
    __shared__ float outv[D_];
    __shared__ float red[32];

    int fXs = detect_wave_256(Xs);
    int fXi = detect_wave_256(Xitem);
    int fOr = detect_wave_256(origin);
    int fz  = detect_wave_64(zv);
    int fMk = detect_mask_u8(maskv);

    const unsigned short* Xg16 = (const unsigned short*)Xs + (size_t)b * S_ * D_;
    const float*          Xg32 = (const float*)Xs + (size_t)b * S_ * D_;

    // --- length via 4 wave ballots (every wave computes it; no LDS) ---
    int len = 0;
#pragma unroll
    for (int k = 0; k < 4; ++k) {
        int s = lane + 64 * k;
        int nzv = 0;
        if (s < S_)
            nzv = fMk ? (((const unsigned char*)maskv)[(size_t)b * S_ + s] != 0)
                      : (((const int*)maskv)[(size_t)b * S_ + s] != 0);
        len += __popcll(__ballot(nzv));
    }
    int last = len - 1;

    // --- per-wave constants: B fragments (regs), z slice, pb base, Xitem ---
    int nt = wv;
    bf16x8 bfr[4];
#pragma unroll
    for (int kks = 0; kks < 4; ++kks)
        bfr[kks] = __builtin_bit_cast(bf16x8,
            *(const short8*)(WeTf + (size_t)((((nt << 2) + kks) << 6) + lane) * 8));
    float zl = ld1(zv, fz, nt * 16 + mrow);
    const float4* pb4 = (const float4*)pbL;
    float xiv = (t < D_) ? ld1(Xitem, fXi, (size_t)b * D_ + t) : 0.f;

#define LOADA(MT, AF)                                                              \
    {                                                                              \
        int r_ = (MT) * 16 + mrow; if (r_ > 199) r_ = 199;                         \
        if (fXs) {                                                                 \
            const unsigned short* p_ = Xg16 + (size_t)r_ * D_ + quad * 8;          \
            _Pragma("unroll")                                                      \
            for (int kk_ = 0; kk_ < 4; ++kk_)                                      \
                AF[kk_] = __builtin_bit_cast(bf16x8, *(const short8*)(p_ + kk_ * 32)); \
        } else {                                                                   \
            const float* p_ = Xg32 + (size_t)r_ * D_ + quad * 8;                   \
            _Pragma("unroll")                                                      \
            for (int kk_ = 0; kk_ < 4; ++kk_) {                                    \
                float4 a_ = ((const float4*)(p_ + kk_ * 32))[0];                   \
                float4 b2_ = ((const float4*)(p_ + kk_ * 32))[1];                  \
                short8 v_;                                                         \
                v_[0] = (short)f2bf(a_.x); v_[1] = (short)f2bf(a_.y);              \
                v_[2] = (short)f2bf(a_.z); v_[3] = (short)f2bf(a_.w);              \
                v_[4] = (short)f2bf(b2_.x); v_[5] = (short)f2bf(b2_.y);            \
                v_[6] = (short)f2bf(b2_.z); v_[7] = (short)f2bf(b2_.w);            \
                AF[kk_] = __builtin_bit_cast(bf16x8, v_);                          \
            }                                                                      \
        }                                                                          \
    }

    // --- phase A: 13 m-tiles, wave computes its nt partial of the z-dot ---
    float* sp = ubuf;   // [8][208]
    for (int mt = 0; mt < 13; ++mt) {
        float4 pbc = pb4[(size_t)(mt * 8 + nt) * 64 + lane];
        bf16x8 afc[4];
        LOADA(mt, afc);
        floatx4 acc;
        acc[0] = pbc.x; acc[1] = pbc.y; acc[2] = pbc.z; acc[3] = pbc.w;
#pragma unroll
        for (int kks = 0; kks < 4; ++kks)
            acc = __builtin_amdgcn_mfma_f32_16x16x32_bf16(afc[kks], bfr[kks], acc, 0, 0, 0);
#pragma unroll
        for (int r = 0; r < 4; ++r) {
            float v = fast_tanh(acc[r]) * zl;
            v += __shfl_xor(v, 1, 64);
            v += __shfl_xor(v, 2, 64);
            v += __shfl_xor(v, 4, 64);
            v += __shfl_xor(v, 8, 64);
            int s = mt * 16 + quad * 4 + r;
            if (mrow == 0 && s < S_) sp[nt * 208 + s] = v;
        }
    }
    __syncthreads();                                           // S1: sp ready

    // --- softmax by wave 0 (registers + shuffles), writes attn[0..255] ---
    if (wv == 0) {
        float s0 = 0.f, s1 = 0.f, s2 = 0.f, s3 = 0.f;
#pragma unroll
        for (int n8 = 0; n8 < 8; ++n8) {
            float4 q = *(const float4*)(sp + n8 * 208 + lane * 4);
            s0 += q.x; s1 += q.y; s2 += q.z; s3 += q.w;
        }
        int sb = lane * 4;
        float m0 = (sb + 0 < len) ? s0 : -INFINITY;
        float m1 = (sb + 1 < len) ? s1 : -INFINITY;
        float m2 = (sb + 2 < len) ? s2 : -INFINITY;
        float m3 = (sb + 3 < len) ? s3 : -INFINITY;
        float m = fmaxf(fmaxf(m0, m1), fmaxf(m2, m3));
#pragma unroll
        for (int off = 32; off; off >>= 1) m = fmaxf(m, __shfl_xor(m, off, 64));
        float e0 = (sb + 0 < len) ? __expf(s0 - m) : 0.f;
        float e1 = (sb + 1 < len) ? __expf(s1 - m) : 0.f;
        float e2 = (sb + 2 < len) ? __expf(s2 - m) : 0.f;
        float e3 = (sb + 3 < len) ? __expf(s3 - m) : 0.f;
        float l = e0 + e1 + e2 + e3;
#pragma unroll
        for (int off = 32; off; off >>= 1) l += __shfl_xor(l, off, 64);
        float inv = 1.0f / l;
        float4 av = {e0 * inv, e1 * inv, e2 * inv, e3 * inv};
        *(float4*)(attn + sb) = av;
    }
    __syncthreads();                                           // S2: attn ready

    // --- weighted sum: partial[32][128] from GLOBAL X (L2/L3-hot) ---
    {
        int spi = t >> 4;          // 0..31
        int d8 = (t & 15) * 8;     // 0..120
        float a0 = 0.f, a1 = 0.f, a2 = 0.f, a3 = 0.f;
        float a4 = 0.f, a5 = 0.f, a6 = 0.f, a7 = 0.f;
        if (fXs) {
            for (int s = spi; s < S_; s += 32) {
                float ww = attn[s];
                short8 v2 = *(const short8*)(Xg16 + (size_t)s * D_ + d8);
                a0 = fmaf(ww, bf2f((unsigned short)v2[0]), a0);
                a1 = fmaf(ww, bf2f((unsigned short)v2[1]), a1);
                a2 = fmaf(ww, bf2f((unsigned short)v2[2]), a2);
                a3 = fmaf(ww, bf2f((unsigned short)v2[3]), a3);
                a4 = fmaf(ww, bf2f((unsigned short)v2[4]), a4);
                a5 = fmaf(ww, bf2f((unsigned short)v2[5]), a5);
                a6 = fmaf(ww, bf2f((unsigned short)v2[6]), a6);
                a7 = fmaf(ww, bf2f((unsigned short)v2[7]), a7);
            }
        } else {
            for (int s = spi; s < S_; s += 32) {
                float ww = attn[s];
                const float* p = Xg32 + (size_t)s * D_ + d8;
                float4 u0 = ((const float4*)p)[0], u1 = ((const float4*)p)[1];
                a0 = fmaf(ww, u0.x, a0); a1 = fmaf(ww, u0.y, a1);
                a2 = fmaf(ww, u0.z, a2); a3 = fmaf(ww, u0.w, a3);
                a4 = fmaf(ww, u1.x, a4); a5 = fmaf(ww, u1.y, a5);
                a6 = fmaf(ww, u1.z, a6); a7 = fmaf(ww, u1.w, a7);
            }
        }
        float4 w0 = {a0, a1, a2, a3}, w1 = {a4, a5, a6, a7};
        *(float4*)(ubuf + spi * D_ + d8)     = w0;   // sp is dead now
        *(float4*)(ubuf + spi * D_ + d8 + 4) = w1;
    }
    __syncthreads();                                           // S3: partial ready

    // --- epilogue reductions (waves 0-1), out write ---
    if (t < D_) {
        float att = 0.f;
#pragma unroll
        for (int p = 0; p < 32; ++p) att += ubuf[p * D_ + t];
        float xl = fXs ? bf2f(Xg16[(size_t)last * D_ + t])
                       : Xg32[(size_t)last * D_ + t];
        float lv = attn[last] * xl;
        float ov = att - lv;                 // out_vec = attention_output - last_vec
        outv[t] = ov;
        out[(size_t)b * (D_ + 1) + t] = att;
        float r0 = att * xiv;                // inner
        float r1 = lv * lv, r2 = lv * ov, r3 = ov * ov;
#pragma unroll
        for (int off = 32; off; off >>= 1) {
            r0 += __shfl_xor(r0, off, 64);
            r1 += __shfl_xor(r1, off, 64);
            r2 += __shfl_xor(r2, off, 64);
            r3 += __shfl_xor(r3, off, 64);
        }
        if (lane == 0) { red[wv] = r0; red[8 + wv] = r1; red[16 + wv] = r2; red[24 + wv] = r3; }
    }
    __syncthreads();                                           // S4: red/outv ready, ubuf free
    float vv = red[24] + red[25];            // ||out_vec||^2 (all threads)
    if (t == 0) {
        out[(size_t)b * (D_ + 1) + D_] = red[0] + red[1];
        float ll = red[8] + red[9], lo = red[16] + red[17];
        float cosv = lo / (sqrtf(fmaxf(ll, 1e-12f)) * sqrtf(fmaxf(vv, 1e-12f)));
        float pl = 0.5f * (1.f - cosv);
        pos_loss[b] = log1pf(expf(-pl));
    }

    // --- neg losses: thread (nn = t>>3, part = t&7) eighth-dot; origin loaded here ---
    {
        int nn = t >> 3, part = t & 7;
        float o_f[16];
        if (fOr) {
            const unsigned short* p = (const unsigned short*)origin + ((size_t)b * N_ + nn) * D_ + part * 16;
#pragma unroll
            for (int j = 0; j < 2; ++j) {
                uint4 u = *(const uint4*)(p + j * 8);
                o_f[j*8+0] = bf2f((unsigned short)(u.x & 0xffff));
                o_f[j*8+1] = bf2f((unsigned short)(u.x >> 16));
                o_f[j*8+2] = bf2f((unsigned short)(u.y & 0xffff));
                o_f[j*8+3] = bf2f((unsigned short)(u.y >> 16));
                o_f[j*8+4] = bf2f((unsigned short)(u.z & 0xffff));
                o_f[j*8+5] = bf2f((unsigned short)(u.z >> 16));
                o_f[j*8+6] = bf2f((unsigned short)(u.w & 0xffff));
                o_f[j*8+7] = bf2f((unsigned short)(u.w >> 16));
            }
        } else {
            const float* p = (const float*)origin + ((size_t)b * N_ + nn) * D_ + part * 16;
#pragma unroll
            for (int j = 0; j < 4; ++j) {
                float4 v = *(const float4*)(p + j * 4);
                o_f[j*4+0] = v.x; o_f[j*4+1] = v.y; o_f[j*4+2] = v.z; o_f[j*4+3] = v.w;
            }
        }
        float o_oo = 0.f, o_ov = 0.f;
#pragma unroll
        for (int j = 0; j < 16; ++j) {
            float wv_ = outv[part * 16 + j];
            o_oo = fmaf(o_f[j], o_f[j], o_oo);
            o_ov = fmaf(o_f[j], wv_, o_ov);
        }
        float* p_oo = ubuf;          // [8][64]
        float* p_ov = ubuf + 512;    // [8][64]
        p_oo[part * 64 + nn] = o_oo;
        p_ov[part * 64 + nn] = o_ov;
        __syncthreads();                                       // S5
        if (t < 64) {
            float oo = 0.f, ov2 = 0.f;
#pragma unroll
            for (int p8 = 0; p8 < 8; ++p8) { oo += p_oo[p8 * 64 + t]; ov2 += p_ov[p8 * 64 + t]; }
            float cosn = ov2 / (sqrtf(fmaxf(oo, 1e-12f)) * sqrtf(fmaxf(vv, 1e-12f)));
            float nl = 0.5f * (1.f - cosn);
            float nloss = log1pf(expf(nl));
#pragma unroll
            for (int off = 32; off; off >>= 1) nloss += __shfl_xor(nloss, off, 64);
            if (t == 0) neg_sum[b] = nloss;
        }
    }
#undef LOADA
}

// ---------------- K3: aux[b] = sum_b'(pos_loss) + neg_sum[b] (f32) ----------------
__global__ __launch_bounds__(1024) void final_kernel(
    const float* __restrict__ pos_loss,
    const float* __restrict__ neg_sum,
    float* __restrict__ out)
{
    __shared__ float red[16];
    int t = threadIdx.x;
    float v = pos_loss[t];
    for (int off = 32; off; off >>= 1) v += __shfl_xor(v, off, 64);
    if ((t & 63) == 0) red[t >> 6] = v;
    __syncthreads();
    if (t == 0) {
        float s = 0.f;
#pragma unroll
        for (int i = 0; i < 16; ++i) s += red[i];
        red[0] = s;
    }
    __syncthreads();
    out[(size_t)B_ * (D_ + 1) + t] = red[0] + neg_sum[t];
}

extern "C" void kernel_launch(void* const* d_in, const int* in_sizes, int n_in,
                              void* d_out, int out_size, void* d_ws, size_t ws_size,
                              hipStream_t stream) {
    const void* Xs     = d_in[0]; // X_series [B,S,D]
    const void* pos    = d_in[1]; // pos_series [S,D]
    const void* Xitem  = d_in[2]; // X_item [B,D]
    const void* mask   = d_in[3]; // valid_mask [B,S]
    const void* origin = d_in[4]; // origin [B,N,D]
    const void* Wp     = d_in[5]; // [D,H]
    const void* We     = d_in[6]; // [D,H]
    const void* zv     = d_in[7]; // [H]

    unsigned short* WeTf = (unsigned short*)d_ws;                  // 32 KB swizzled
    float* pbL      = (float*)((char*)d_ws + 32768);               // 13*8*64*4 f32 = 104 KB
    float* pos_loss = pbL + 13 * 8 * 64 * 4;                       // 1024 f32
    float* neg_sum  = pos_loss + B_;                               // 1024 f32
    float* out = (float*)d_out;                                    // f32 output

    prep_kernel<<<201, 128, 0, stream>>>(We, pos, Wp, WeTf, pbL);
    fused_kernel<<<B_, 512, 0, stream>>>(Xs, Xitem, mask, origin, WeTf, pbL, zv,
                                         pos_loss, neg_sum, out);
    final_kernel<<<1, 1024, 0, stream>>>(pos_loss, neg_sum, out);
}

// Round 7
// 302.251 us; speedup vs baseline: 1.0544x; 1.0544x over previous
//
#include <hip/hip_runtime.h>
#include <hip/hip_bf16.h>
#include <math.h>

#define B_ 1024
#define S_ 200
#define D_ 128
#define H_ 128
#define N_ 64

typedef __attribute__((ext_vector_type(8))) short short8;
typedef __attribute__((ext_vector_type(8))) __bf16 bf16x8;
typedef __attribute__((ext_vector_type(4))) float floatx4;

typedef __attribute__((address_space(1))) void gvoid_t;
typedef __attribute__((address_space(3))) void lvoid_t;

static __device__ __forceinline__ float bf2f(unsigned short u) {
    union { unsigned int i; float f; } v; v.i = ((unsigned int)u) << 16; return v.f;
}
static __device__ __forceinline__ unsigned short f2bf(float f) {
    union { float f; unsigned int u; } v; v.f = f;
    unsigned int u = v.u;
    return (unsigned short)((u + 0x7FFFu + ((u >> 16) & 1u)) >> 16);   // RNE
}
static __device__ __forceinline__ float ld1(const void* p, int isbf, size_t i) {
    return isbf ? bf2f(((const unsigned short*)p)[i]) : ((const float*)p)[i];
}
static __device__ __forceinline__ float fast_tanh(float x) {
    float t = __expf(2.0f * x);
    return 1.0f - 2.0f * __builtin_amdgcn_rcpf(t + 1.0f);   // err ~2e-5
}
static __device__ __forceinline__ void gload_lds16(const void* g, void* l) {
    __builtin_amdgcn_global_load_lds((const gvoid_t*)g, (lvoid_t*)l, 16, 0, 0);
}

// ---- wave-local dtype detection (no barriers; every wave computes the same flag) ----
static __device__ __forceinline__ int detect_wave_256(const void* p) {
    int lane = threadIdx.x & 63;
    uint4 w = ((const uint4*)p)[lane];          // 256 words sampled per wave
    unsigned int ws[4] = {w.x, w.y, w.z, w.w};
    int pass = 0;
#pragma unroll
    for (int k = 0; k < 4; ++k) {
        unsigned int e = (ws[k] >> 7) & 0xFF;   // exponent of lo-bf16 if data is bf16
        pass += (e == 0 || (e >= 96 && e <= 140)) ? 1 : 0;
    }
#pragma unroll
    for (int off = 32; off; off >>= 1) pass += __shfl_xor(pass, off, 64);
    return pass * 4 >= 256 * 3;
}
static __device__ __forceinline__ int detect_wave_64(const void* p) {
    int lane = threadIdx.x & 63;
    unsigned int w = ((const unsigned int*)p)[lane];   // 64 words
    unsigned int e = (w >> 7) & 0xFF;
    int pass = (e == 0 || (e >= 96 && e <= 140)) ? 1 : 0;
#pragma unroll
    for (int off = 32; off; off >>= 1) pass += __shfl_xor(pass, off, 64);
    return pass * 4 >= 64 * 3;
}
static __device__ __forceinline__ int detect_mask_u8(const void* p) {
    int lane = threadIdx.x & 63;
    uint4 w = ((const uint4*)p)[lane];          // first 1 KB of mask
    unsigned int x = (w.x | w.y | w.z | w.w) & 0xFFFFFF00u;  // nonzero high bytes => u8
    return (__ballot(x != 0) != 0ULL) ? 1 : 0;
}

// ---------------- prep: block 0 -> WeTf (fragment-swizzled) + zero gsum/cnt;
//                  blocks 1..200 -> pbL rows ----
// WeTf layout: frag = nt*4+kks; WeTf[(frag*64+lane)*8+j] = We[kks*32+(lane>>4)*8+j][nt*16+(lane&15)]
// pbL layout (per-lane C-fragment order): float idx ((mt*8+nt)*64 + quad*16 + mrow)*4 + reg
//   = pb[s = mt*16+quad*4+reg][h = nt*16+mrow]. mt=12 entries with s>=200 are zero-filled.
__global__ __launch_bounds__(128) void prep_kernel(
    const void* __restrict__ We, const void* __restrict__ pos,
    const void* __restrict__ Wp,
    unsigned short* __restrict__ WeTf, float* __restrict__ pbL,
    float* __restrict__ gsum, unsigned int* __restrict__ cnt)
{
    int blk = blockIdx.x, t = threadIdx.x;
    __shared__ unsigned short T[128][136];
    __shared__ float prow[D_];
    __shared__ int fl[2];
    if (blk == 0) {
        if (t == 0) { *gsum = 0.f; *cnt = 0u; }
        if (t < 64) { int f = detect_wave_256(We); if (t == 0) fl[0] = f; }
        __syncthreads();
        int fWe = fl[0];
        for (int c = t; c < 2048; c += 128) {
            int d = c >> 4, h8 = (c & 15) * 8;
            short8 v;
            if (fWe) {
                v = *(const short8*)((const unsigned short*)We + d * H_ + h8);
            } else {
                const float* p = (const float*)We + d * H_ + h8;
                float4 a = ((const float4*)p)[0], b = ((const float4*)p)[1];
                v[0] = (short)f2bf(a.x); v[1] = (short)f2bf(a.y);
                v[2] = (short)f2bf(a.z); v[3] = (short)f2bf(a.w);
                v[4] = (short)f2bf(b.x); v[5] = (short)f2bf(b.y);
                v[6] = (short)f2bf(b.z); v[7] = (short)f2bf(b.w);
            }
            *(short8*)(&T[d][h8]) = v;
        }
        __syncthreads();
        for (int i = t; i < 2048; i += 128) {
            int frag = i >> 6, ln = i & 63;
            int nt = frag >> 2, kks = frag & 3;
            int h = nt * 16 + (ln & 15);
            int dbase = kks * 32 + (ln >> 4) * 8;
            short8 v;
#pragma unroll
            for (int j = 0; j < 8; ++j) v[j] = (short)T[dbase + j][h];
            *(short8*)(WeTf + (size_t)i * 8) = v;
        }
        // zero-fill pbL entries for mt=12, s_local >= 8 (s = 200..207)
        for (int i = t; i < 1024; i += 128) {
            int nt = i >> 7, j = i & 127;
            int q = 2 + (j >> 6), m = (j >> 2) & 15, r = j & 3;
            pbL[(((96 + nt) * 64 + q * 16 + m) << 2) + r] = 0.f;
        }
    } else {
        if (t < 64)       { int f = detect_wave_256(pos); if (t == 0)  fl[0] = f; }
        else if (t < 128) { int f = detect_wave_256(Wp);  if (t == 64) fl[1] = f; }
        __syncthreads();
        int fPos = fl[0], fWp = fl[1];
        int s = blk - 1, h = t;
        prow[h] = ld1(pos, fPos, (size_t)s * D_ + h);
        __syncthreads();
        float acc = 0.f;
        if (fWp) {
            const unsigned short* W = (const unsigned short*)Wp;
            for (int d = 0; d < D_; ++d) acc = fmaf(prow[d], bf2f(W[d * H_ + h]), acc);
        } else {
            const float* W = (const float*)Wp;
            for (int d = 0; d < D_; ++d) acc = fmaf(prow[d], W[d * H_ + h], acc);
        }
        int mt = s >> 4, qr = s & 15;
        int idx = (((mt * 8 + (h >> 4)) * 64 + (qr >> 2) * 16 + (h & 15)) << 2) + (qr & 3);
        pbL[idx] = acc;
    }
}

// ---------------- fused: block per b, 8 waves, LDS-staged X (53.9 KB -> 3 blocks/CU) ----
// Xsh: LDS(s,e) = X[s][e ^ ((s&7)<<3)] (16B-chunk XOR swizzle, linear dest + pre-swizzled src).
// sp/oacc accumulated via LDS atomics (kills the 16KB partial buffers of the r2 version).
// Last block writes the aux row (replaces final_kernel).
__global__ __launch_bounds__(512, 6) void fused_kernel(
    const void* __restrict__ Xs, const void* __restrict__ Xitem,
    const void* __restrict__ maskv, const void* __restrict__ origin,
    const unsigned short* __restrict__ WeTf, const float* __restrict__ pbL,
    const void* __restrict__ zv,
    float* __restrict__ neg_sum, float* __restrict__ gsum,
    unsigned int* __restrict__ cnt, float* __restrict__ out)
{
    int b = blockIdx.x, t = threadIdx.x;
    int wv = t >> 6, lane = t & 63;
    int quad = lane >> 4, mrow = lane & 15;

    __shared__ __align__(16) unsigned short Xsh[S_ * D_];   // 51200 B
    __shared__ __align__(16) float ures[528];   // attn[0..199] | sp[200..399] | oacc[400..527]
    __shared__ float outv[D_];
    __shared__ float red[40];
    __shared__ int lastflag;

    float* attnb = ures;
    float* sp    = ures + 200;
    float* oacc  = ures + 400;

    int fXs = detect_wave_256(Xs);
    int fXi = detect_wave_256(Xitem);
    int fOr = detect_wave_256(origin);
    int fz  = detect_wave_64(zv);
    int fMk = detect_mask_u8(maskv);

    const unsigned short* Xg16 = (const unsigned short*)Xs + (size_t)b * S_ * D_;
    const float*          Xg32 = (const float*)Xs + (size_t)b * S_ * D_;

    // zero the LDS atomic accumulators (visible after S1 barrier)
    if (t < 200) sp[t] = 0.f;
    if (t < 128) oacc[t] = 0.f;

    // --- length via 4 wave ballots ---
    int len = 0;
#pragma unroll
    for (int k = 0; k < 4; ++k) {
        int s = lane + 64 * k;
        int nzv = 0;
        if (s < S_)
            nzv = fMk ? (((const unsigned char*)maskv)[(size_t)b * S_ + s] != 0)
                      : (((const int*)maskv)[(size_t)b * S_ + s] != 0);
        len += __popcll(__ballot(nzv));
    }
    int last = len - 1;

    // --- per-wave constants ---
    int nt = wv;
    bf16x8 bfr[4];
#pragma unroll
    for (int kks = 0; kks < 4; ++kks)
        bfr[kks] = __builtin_bit_cast(bf16x8,
            *(const short8*)(WeTf + (size_t)((((nt << 2) + kks) << 6) + lane) * 8));
    float zl = ld1(zv, fz, nt * 16 + mrow);
    const float4* pbw = (const float4*)pbL + nt * 64 + lane;
    float xiv = (t < D_) ? ld1(Xitem, fXi, (size_t)b * D_ + t) : 0.f;

    // --- staging phase 1: tiles 0..3 (i < 1024); f32 path stages everything here ---
    if (fXs) {
#pragma unroll
        for (int j = 0; j < 2; ++j) {
            int i = t + j * 512;
            int s = i >> 4, c8 = (i & 15) * 8;
            gload_lds16(Xg16 + (size_t)s * D_ + (c8 ^ ((s & 7) << 3)), Xsh + (size_t)i * 8);
        }
    } else {
        for (int i = t; i < S_ * 16; i += 512) {
            int s = i >> 4, c8 = (i & 15) * 8;
            const float* p = Xg32 + (size_t)s * D_ + c8;
            float4 a = ((const float4*)p)[0], c = ((const float4*)p)[1];
            short8 v;
            v[0] = (short)f2bf(a.x); v[1] = (short)f2bf(a.y);
            v[2] = (short)f2bf(a.z); v[3] = (short)f2bf(a.w);
            v[4] = (short)f2bf(c.x); v[5] = (short)f2bf(c.y);
            v[6] = (short)f2bf(c.z); v[7] = (short)f2bf(c.w);
            *(short8*)(Xsh + s * D_ + (c8 ^ ((s & 7) << 3))) = v;
        }
    }
    float4 pbc = pbw[0];

    asm volatile("s_waitcnt vmcnt(0)" ::: "memory");
    __syncthreads();                                           // S1: tiles 0..3 + zeros ready

    // --- staging phase 2: tiles 4..12, in flight under tiles 0..3 compute ---
    if (fXs) {
#pragma unroll
        for (int j = 2; j < 7; ++j) {
            int i = t + j * 512;
            if (i < S_ * 16) {
                int s = i >> 4, c8 = (i & 15) * 8;
                gload_lds16(Xg16 + (size_t)s * D_ + (c8 ^ ((s & 7) << 3)), Xsh + (size_t)i * 8);
            }
        }
    }

    // --- phase A: 13 m-tiles; scores accumulated into sp via LDS atomics ---
    for (int mt = 0; mt < 13; ++mt) {
        if (mt == 4) {
            asm volatile("s_waitcnt vmcnt(0)" ::: "memory");
            __syncthreads();                                   // S1b: tiles 4..12 ready
        }
        float4 pbn = pbc;
        if (mt < 12) pbn = pbw[(size_t)(mt + 1) * 512];
        int r = mt * 16 + mrow; if (r > 199) r = 199;          // clamp tail (masked later)
        int rbase = r * D_, rx = (r & 7) << 3;
        floatx4 acc;
        acc[0] = pbc.x; acc[1] = pbc.y; acc[2] = pbc.z; acc[3] = pbc.w;
#pragma unroll
        for (int kks = 0; kks < 4; ++kks) {
            bf16x8 af = __builtin_bit_cast(bf16x8,
                *(const short8*)(Xsh + rbase + ((kks * 32 + quad * 8) ^ rx)));
            acc = __builtin_amdgcn_mfma_f32_16x16x32_bf16(af, bfr[kks], acc, 0, 0, 0);
        }
#pragma unroll
        for (int rr = 0; rr < 4; ++rr) {
            float v = fast_tanh(acc[rr]) * zl;
            v += __shfl_xor(v, 1, 64);
            v += __shfl_xor(v, 2, 64);
            v += __shfl_xor(v, 4, 64);
            v += __shfl_xor(v, 8, 64);
            int s = mt * 16 + quad * 4 + rr;
            if (mrow == 0 && s < S_) atomicAdd(&sp[s], v);
        }
        pbc = pbn;
    }
    __syncthreads();                                           // S2: sp complete

    // --- softmax by wave 0 (lane<50 owns 4 s) ---
    if (wv == 0) {
        int sb = lane * 4;
        float4 q = {0.f, 0.f, 0.f, 0.f};
        if (lane < 50) q = *(const float4*)(sp + sb);
        float m0 = (sb + 0 < len) ? q.x : -INFINITY;
        float m1 = (sb + 1 < len) ? q.y : -INFINITY;
        float m2 = (sb + 2 < len) ? q.z : -INFINITY;
        float m3 = (sb + 3 < len) ? q.w : -INFINITY;
        float m = fmaxf(fmaxf(m0, m1), fmaxf(m2, m3));
#pragma unroll
        for (int off = 32; off; off >>= 1) m = fmaxf(m, __shfl_xor(m, off, 64));
        float e0 = (sb + 0 < len) ? __expf(q.x - m) : 0.f;
        float e1 = (sb + 1 < len) ? __expf(q.y - m) : 0.f;
        float e2 = (sb + 2 < len) ? __expf(q.z - m) : 0.f;
        float e3 = (sb + 3 < len) ? __expf(q.w - m) : 0.f;
        float l = e0 + e1 + e2 + e3;
#pragma unroll
        for (int off = 32; off; off >>= 1) l += __shfl_xor(l, off, 64);
        float inv = 1.0f / l;
        if (lane < 50) {
            float4 av = {e0 * inv, e1 * inv, e2 * inv, e3 * inv};
            *(float4*)(attnb + sb) = av;
        }
    }
    __syncthreads();                                           // S3: attn ready

    // --- weighted sum into oacc via LDS atomics; all 512 threads ---
    {
        int d = t & 127, g = t >> 7;     // 4 slices x 128 d
        float a = 0.f;
        if (fXs) {
            for (int s = g; s < S_; s += 4)
                a = fmaf(attnb[s], bf2f(Xsh[s * D_ + (d ^ ((s & 7) << 3))]), a);
        } else {
            for (int s = g; s < S_; s += 4)
                a = fmaf(attnb[s], Xg32[(size_t)s * D_ + d], a);
        }
        atomicAdd(&oacc[d], a);
    }
    __syncthreads();                                           // S4: oacc ready

    // --- epilogue reductions, out write ---
    if (t < D_) {
        float att = oacc[t];
        float xl = fXs ? bf2f(Xsh[last * D_ + (t ^ ((last & 7) << 3))])
                       : Xg32[(size_t)last * D_ + t];
        float lv = attnb[last] * xl;
        float ov = att - lv;                 // out_vec = attention_output - last_vec
        outv[t] = ov;
        out[(size_t)b * (D_ + 1) + t] = att;
        float r0 = att * xiv;                // inner
        float r1 = lv * lv, r2 = lv * ov, r3 = ov * ov;
#pragma unroll
        for (int off = 32; off; off >>= 1) {
            r0 += __shfl_xor(r0, off, 64);
            r1 += __shfl_xor(r1, off, 64);
            r2 += __shfl_xor(r2, off, 64);
            r3 += __shfl_xor(r3, off, 64);
        }
        if (lane == 0) { red[wv] = r0; red[8 + wv] = r1; red[16 + wv] = r2; red[24 + wv] = r3; }
    }
    __syncthreads();                                           // S5
    float vv = red[24] + red[25];            // ||out_vec||^2 (all threads)
    if (t == 0) {
        out[(size_t)b * (D_ + 1) + D_] = red[0] + red[1];
        float ll = red[8] + red[9], lo = red[16] + red[17];
        float cosv = lo / (sqrtf(fmaxf(ll, 1e-12f)) * sqrtf(fmaxf(vv, 1e-12f)));
        float pl = 0.5f * (1.f - cosv);
        atomicAdd(gsum, log1pf(expf(-pl)));  // global pos-loss sum
    }

    // --- neg losses: thread (nn = t>>3, part = t&7); pure shuffle reduction ---
    {
        int nn = t >> 3, part = t & 7;
        float o_f[16];
        if (fOr) {
            const unsigned short* p = (const unsigned short*)origin + ((size_t)b * N_ + nn) * D_ + part * 16;
#pragma unroll
            for (int j = 0; j < 2; ++j) {
                uint4 u = *(const uint4*)(p + j * 8);
                o_f[j*8+0] = bf2f((unsigned short)(u.x & 0xffff));
                o_f[j*8+1] = bf2f((unsigned short)(u.x >> 16));
                o_f[j*8+2] = bf2f((unsigned short)(u.y & 0xffff));
                o_f[j*8+3] = bf2f((unsigned short)(u.y >> 16));
                o_f[j*8+4] = bf2f((unsigned short)(u.z & 0xffff));
                o_f[j*8+5] = bf2f((unsigned short)(u.z >> 16));
                o_f[j*8+6] = bf2f((unsigned short)(u.w & 0xffff));
                o_f[j*8+7] = bf2f((unsigned short)(u.w >> 16));
            }
        } else {
            const float* p = (const float*)origin + ((size_t)b * N_ + nn) * D_ + part * 16;
#pragma unroll
            for (int j = 0; j < 4; ++j) {
                float4 v = *(const float4*)(p + j * 4);
                o_f[j*4+0] = v.x; o_f[j*4+1] = v.y; o_f[j*4+2] = v.z; o_f[j*4+3] = v.w;
            }
        }
        float o_oo = 0.f, o_ov = 0.f;
#pragma unroll
        for (int j = 0; j < 16; ++j) {
            float wv_ = outv[part * 16 + j];
            o_oo = fmaf(o_f[j], o_f[j], o_oo);
            o_ov = fmaf(o_f[j], wv_, o_ov);
        }
        // reduce across the 8 'part' lanes (contiguous within the wave)
        o_oo += __shfl_xor(o_oo, 1, 64); o_ov += __shfl_xor(o_ov, 1, 64);
        o_oo += __shfl_xor(o_oo, 2, 64); o_ov += __shfl_xor(o_ov, 2, 64);
        o_oo += __shfl_xor(o_oo, 4, 64); o_ov += __shfl_xor(o_ov, 4, 64);
        float ns = 0.f;
        if (part == 0) {
            float cosn = o_ov / (sqrtf(fmaxf(o_oo, 1e-12f)) * sqrtf(fmaxf(vv, 1e-12f)));
            float nl = 0.5f * (1.f - cosn);
            ns = log1pf(expf(nl));
        }
        ns += __shfl_xor(ns, 8, 64);
        ns += __shfl_xor(ns, 16, 64);
        ns += __shfl_xor(ns, 32, 64);
        if (lane == 0) red[32 + wv] = ns;
    }
    __syncthreads();                                           // S6
    if (t == 0) {
        float nsum = red[32] + red[33] + red[34] + red[35]
                   + red[36] + red[37] + red[38] + red[39];
        neg_sum[b] = nsum;
        __threadfence();
        unsigned int my = atomicAdd(cnt, 1u);
        lastflag = (my == B_ - 1) ? 1 : 0;
    }
    __syncthreads();                                           // S7
    if (lastflag) {                                            // last block writes aux row
        __threadfence();
        float gs = *(volatile float*)gsum;
        for (int b2 = t; b2 < B_; b2 += 512)
            out[(size_t)B_ * (D_ + 1) + b2] = gs + neg_sum[b2];
    }
}

extern "C" void kernel_launch(void* const* d_in, const int* in_sizes, int n_in,
                              void* d_out, int out_size, void* d_ws, size_t ws_size,
                              hipStream_t stream) {
    const void* Xs     = d_in[0]; // X_series [B,S,D]
    const void* pos    = d_in[1]; // pos_series [S,D]
    const void* Xitem  = d_in[2]; // X_item [B,D]
    const void* mask   = d_in[3]; // valid_mask [B,S]
    const void* origin = d_in[4]; // origin [B,N,D]
    const void* Wp     = d_in[5]; // [D,H]
    const void* We     = d_in[6]; // [D,H]
    const void* zv     = d_in[7]; // [H]

    unsigned short* WeTf = (unsigned short*)d_ws;                  // 32 KB swizzled
    float* pbL      = (float*)((char*)d_ws + 32768);               // 13*8*64*4 f32 = 104 KB
    float* neg_sum  = pbL + 13 * 8 * 64 * 4;                       // 1024 f32
    float* gsum     = neg_sum + B_;                                // 1 f32
    unsigned int* cnt = (unsigned int*)(gsum + 1);                 // 1 u32
    float* out = (float*)d_out;                                    // f32 output

    prep_kernel<<<201, 128, 0, stream>>>(We, pos, Wp, WeTf, pbL, gsum, cnt);
    fused_kernel<<<B_, 512, 0, stream>>>(Xs, Xitem, mask, origin, WeTf, pbL, zv,
                                         neg_sum, gsum, cnt, out);
}

// Round 8
// 270.528 us; speedup vs baseline: 1.1780x; 1.1173x over previous
//
#include <hip/hip_runtime.h>
#include <hip/hip_bf16.h>
#include <math.h>

#define B_ 1024
#define S_ 200
#define D_ 128
#define H_ 128
#define N_ 64

typedef __attribute__((ext_vector_type(8))) short short8;
typedef __attribute__((ext_vector_type(8))) __bf16 bf16x8;
typedef __attribute__((ext_vector_type(4))) float floatx4;

typedef __attribute__((address_space(1))) void gvoid_t;
typedef __attribute__((address_space(3))) void lvoid_t;

static __device__ __forceinline__ float bf2f(unsigned short u) {
    union { unsigned int i; float f; } v; v.i = ((unsigned int)u) << 16; return v.f;
}
static __device__ __forceinline__ unsigned short f2bf(float f) {
    union { float f; unsigned int u; } v; v.f = f;
    unsigned int u = v.u;
    return (unsigned short)((u + 0x7FFFu + ((u >> 16) & 1u)) >> 16);   // RNE
}
static __device__ __forceinline__ float ld1(const void* p, int isbf, size_t i) {
    return isbf ? bf2f(((const unsigned short*)p)[i]) : ((const float*)p)[i];
}
static __device__ __forceinline__ float fast_tanh(float x) {
    float t = __expf(2.0f * x);
    return 1.0f - 2.0f * __builtin_amdgcn_rcpf(t + 1.0f);   // err ~2e-5
}
static __device__ __forceinline__ void gload_lds16(const void* g, void* l) {
    __builtin_amdgcn_global_load_lds((const gvoid_t*)g, (lvoid_t*)l, 16, 0, 0);
}

// pure-LDS barrier: own-wave lgkm drain + barrier (no vmcnt drain)
#define LBAR() { asm volatile("s_waitcnt lgkmcnt(0)" ::: "memory"); __builtin_amdgcn_s_barrier(); }

// ---- wave-local dtype detection (consumed immediately; drains before staging) ----
static __device__ __forceinline__ int detect_wave_256(const void* p) {
    int lane = threadIdx.x & 63;
    uint4 w = ((const uint4*)p)[lane];
    unsigned int ws[4] = {w.x, w.y, w.z, w.w};
    int pass = 0;
#pragma unroll
    for (int k = 0; k < 4; ++k) {
        unsigned int e = (ws[k] >> 7) & 0xFF;
        pass += (e == 0 || (e >= 96 && e <= 140)) ? 1 : 0;
    }
#pragma unroll
    for (int off = 32; off; off >>= 1) pass += __shfl_xor(pass, off, 64);
    return pass * 4 >= 256 * 3;
}
static __device__ __forceinline__ int detect_wave_64(const void* p) {
    int lane = threadIdx.x & 63;
    unsigned int w = ((const unsigned int*)p)[lane];
    unsigned int e = (w >> 7) & 0xFF;
    int pass = (e == 0 || (e >= 96 && e <= 140)) ? 1 : 0;
#pragma unroll
    for (int off = 32; off; off >>= 1) pass += __shfl_xor(pass, off, 64);
    return pass * 4 >= 64 * 3;
}
static __device__ __forceinline__ int detect_mask_u8(const void* p) {
    int lane = threadIdx.x & 63;
    uint4 w = ((const uint4*)p)[lane];
    unsigned int x = (w.x | w.y | w.z | w.w) & 0xFFFFFF00u;
    return (__ballot(x != 0) != 0ULL) ? 1 : 0;
}

// ---------------- prep: block 0 -> WeTf + pbLh tail + gsum/cnt; blocks 1..200 -> pbLh ----
// WeTf layout: frag = nt*4+kks; WeTf[(frag*64+lane)*8+j] = We[kks*32+(lane>>4)*8+j][nt*16+(lane&15)]
// pbLh (bf16, per-lane C-frag order): ushort idx ((mt*8+nt)*64 + quad*16 + mrow)*4 + reg
//   = pb[s = mt*16+quad*4+reg][h = nt*16+mrow]. mt=12 s>=200 entries zero-filled.
__global__ __launch_bounds__(128) void prep_kernel(
    const void* __restrict__ We, const void* __restrict__ pos,
    const void* __restrict__ Wp,
    unsigned short* __restrict__ WeTf, unsigned short* __restrict__ pbLh,
    float* __restrict__ gsum, unsigned int* __restrict__ cnt)
{
    int blk = blockIdx.x, t = threadIdx.x;
    __shared__ unsigned short T[128][136];
    __shared__ float prow[D_];
    __shared__ int fl[2];
    if (blk == 0) {
        if (t == 0) { *gsum = 0.f; *cnt = 0u; }
        if (t < 64) { int f = detect_wave_256(We); if (t == 0) fl[0] = f; }
        __syncthreads();
        int fWe = fl[0];
        for (int c = t; c < 2048; c += 128) {
            int d = c >> 4, h8 = (c & 15) * 8;
            short8 v;
            if (fWe) {
                v = *(const short8*)((const unsigned short*)We + d * H_ + h8);
            } else {
                const float* p = (const float*)We + d * H_ + h8;
                float4 a = ((const float4*)p)[0], b = ((const float4*)p)[1];
                v[0] = (short)f2bf(a.x); v[1] = (short)f2bf(a.y);
                v[2] = (short)f2bf(a.z); v[3] = (short)f2bf(a.w);
                v[4] = (short)f2bf(b.x); v[5] = (short)f2bf(b.y);
                v[6] = (short)f2bf(b.z); v[7] = (short)f2bf(b.w);
            }
            *(short8*)(&T[d][h8]) = v;
        }
        __syncthreads();
        for (int i = t; i < 2048; i += 128) {
            int frag = i >> 6, ln = i & 63;
            int nt = frag >> 2, kks = frag & 3;
            int h = nt * 16 + (ln & 15);
            int dbase = kks * 32 + (ln >> 4) * 8;
            short8 v;
#pragma unroll
            for (int j = 0; j < 8; ++j) v[j] = (short)T[dbase + j][h];
            *(short8*)(WeTf + (size_t)i * 8) = v;
        }
        // zero-fill pbLh entries for mt=12, s_local >= 8 (s = 200..207)
        for (int i = t; i < 1024; i += 128) {
            int nt = i >> 7, j = i & 127;
            int q = 2 + (j >> 6), m = (j >> 2) & 15, r = j & 3;
            pbLh[(((96 + nt) * 64 + q * 16 + m) << 2) + r] = 0;
        }
    } else {
        if (t < 64)       { int f = detect_wave_256(pos); if (t == 0)  fl[0] = f; }
        else if (t < 128) { int f = detect_wave_256(Wp);  if (t == 64) fl[1] = f; }
        __syncthreads();
        int fPos = fl[0], fWp = fl[1];
        int s = blk - 1, h = t;
        prow[h] = ld1(pos, fPos, (size_t)s * D_ + h);
        __syncthreads();
        float acc = 0.f;
        if (fWp) {
            const unsigned short* W = (const unsigned short*)Wp;
            for (int d = 0; d < D_; ++d) acc = fmaf(prow[d], bf2f(W[d * H_ + h]), acc);
        } else {
            const float* W = (const float*)Wp;
            for (int d = 0; d < D_; ++d) acc = fmaf(prow[d], W[d * H_ + h], acc);
        }
        int mt = s >> 4, qr = s & 15;
        int idx = (((mt * 8 + (h >> 4)) * 64 + (qr >> 2) * 16 + (h & 15)) << 2) + (qr & 3);
        pbLh[idx] = f2bf(acc);
    }
}

// ---------------- fused: block per b, 8 waves, 13-phase vmcnt-laddered staging ----------
// Xsh 208 rows (rows 200..207 = clamped row-199 data, discarded). pb in registers (bf16).
// Per-phase: s_waitcnt vmcnt(12-mt) + raw s_barrier -> tile mt guaranteed in LDS.
__global__ __launch_bounds__(512, 4) void fused_kernel(
    const void* __restrict__ Xs, const void* __restrict__ Xitem,
    const void* __restrict__ maskv, const void* __restrict__ origin,
    const unsigned short* __restrict__ WeTf, const unsigned short* __restrict__ pbLh,
    const void* __restrict__ zv,
    float* __restrict__ neg_sum, float* __restrict__ gsum,
    unsigned int* __restrict__ cnt, float* __restrict__ out)
{
    int b = blockIdx.x, t = threadIdx.x;
    int wv = t >> 6, lane = t & 63;
    int quad = lane >> 4, mrow = lane & 15;

    __shared__ __align__(16) unsigned short Xsh[208 * D_];   // 53248 B
    __shared__ __align__(16) float ubuf[4096];               // sp[8][208] | partial[32][128]
    __shared__ float red4[512];
    __shared__ float attn[200];
    __shared__ float outv[D_];
    __shared__ float red[40];
    __shared__ int lastflag;

    float* sp = ubuf;   // [8][208]

    // --- detects: loads consumed immediately (vmcnt drained before staging) ---
    int fXs = detect_wave_256(Xs);
    int fXi = detect_wave_256(Xitem);
    int fOr = detect_wave_256(origin);
    int fz  = detect_wave_64(zv);
    int fMk = detect_mask_u8(maskv);

    const unsigned short* Xg16 = (const unsigned short*)Xs + (size_t)b * S_ * D_;
    const float*          Xg32 = (const float*)Xs + (size_t)b * S_ * D_;

    // --- K VGPR loads issued BEFORE the stage queue (oldest in vmcnt order) ---
    int nt = wv;
    bf16x8 bfr[4];
#pragma unroll
    for (int kks = 0; kks < 4; ++kks)
        bfr[kks] = __builtin_bit_cast(bf16x8,
            *(const short8*)(WeTf + (size_t)((((nt << 2) + kks) << 6) + lane) * 8));
    float zl = ld1(zv, fz, nt * 16 + mrow);
    uint2 pbh[13];                       // 13 x 4 bf16 = this lane's pb fragments
#pragma unroll
    for (int m2 = 0; m2 < 13; ++m2)
        pbh[m2] = *(const uint2*)(pbLh + (size_t)(((m2 * 8 + nt) * 64 + lane) << 2));
    float xiv = (t < D_) ? ld1(Xitem, fXi, (size_t)b * D_ + t) : 0.f;

    // --- stage queue: 13 gload_lds per wave (lanes<32: 2 rows x 16 chunks each) ---
    if (fXs) {
#pragma unroll
        for (int mt = 0; mt < 13; ++mt) {
            int row = mt * 16 + wv * 2 + (lane >> 4);        // 0..207
            int srow = row < S_ ? row : 199;                 // clamp source (no OOB)
            int c8 = (lane & 15) * 8;
            if (lane < 32)
                gload_lds16(Xg16 + (size_t)srow * D_ + (c8 ^ ((srow & 7) << 3)),
                            Xsh + (size_t)row * D_ + c8);
        }
    } else {
        for (int i = t; i < S_ * 16; i += 512) {
            int s = i >> 4, c8 = (i & 15) * 8;
            const float* p = Xg32 + (size_t)s * D_ + c8;
            float4 a = ((const float4*)p)[0], c = ((const float4*)p)[1];
            short8 v;
            v[0] = (short)f2bf(a.x); v[1] = (short)f2bf(a.y);
            v[2] = (short)f2bf(a.z); v[3] = (short)f2bf(a.w);
            v[4] = (short)f2bf(c.x); v[5] = (short)f2bf(c.y);
            v[6] = (short)f2bf(c.z); v[7] = (short)f2bf(c.w);
            *(short8*)(Xsh + s * D_ + (c8 ^ ((s & 7) << 3))) = v;
        }
        LBAR();                                              // f32 path: all staged
    }

    // --- phase ladder: wait own stage(mt), barrier, compute tile mt ---
#define PHASE(MT, REM)                                                               \
    asm volatile("s_waitcnt vmcnt(" #REM ")" ::: "memory");                          \
    __builtin_amdgcn_s_barrier();                                                    \
    {                                                                                \
        int r_ = (MT) * 16 + mrow;                                                   \
        int rbase_ = r_ * D_, rx_ = (r_ & 7) << 3;                                   \
        floatx4 acc_;                                                                \
        acc_[0] = bf2f((unsigned short)(pbh[MT].x & 0xffff));                        \
        acc_[1] = bf2f((unsigned short)(pbh[MT].x >> 16));                           \
        acc_[2] = bf2f((unsigned short)(pbh[MT].y & 0xffff));                        \
        acc_[3] = bf2f((unsigned short)(pbh[MT].y >> 16));                           \
        _Pragma("unroll")                                                            \
        for (int kks_ = 0; kks_ < 4; ++kks_) {                                       \
            bf16x8 af_ = __builtin_bit_cast(bf16x8,                                  \
                *(const short8*)(Xsh + rbase_ + ((kks_ * 32 + quad * 8) ^ rx_)));    \
            acc_ = __builtin_amdgcn_mfma_f32_16x16x32_bf16(af_, bfr[kks_], acc_, 0, 0, 0); \
        }                                                                            \
        _Pragma("unroll")                                                            \
        for (int rr_ = 0; rr_ < 4; ++rr_) {                                          \
            float v_ = fast_tanh(acc_[rr_]) * zl;                                    \
            v_ += __shfl_xor(v_, 1, 64);                                             \
            v_ += __shfl_xor(v_, 2, 64);                                             \
            v_ += __shfl_xor(v_, 4, 64);                                             \
            v_ += __shfl_xor(v_, 8, 64);                                             \
            int s_ = (MT) * 16 + quad * 4 + rr_;                                     \
            if (mrow == 0 && s_ < S_) sp[nt * 208 + s_] = v_;                        \
        }                                                                            \
    }

    PHASE(0, 12)  PHASE(1, 11)  PHASE(2, 10)  PHASE(3, 9)
    PHASE(4, 8)   PHASE(5, 7)   PHASE(6, 6)   PHASE(7, 5)
    PHASE(8, 4)   PHASE(9, 3)   PHASE(10, 2)  PHASE(11, 1)
    PHASE(12, 0)
#undef PHASE

    // --- post-ladder loads: length (consumed at softmax), origin (consumed at end) ---
    int len = 0;
#pragma unroll
    for (int k = 0; k < 4; ++k) {
        int s = lane + 64 * k;
        int nzv = 0;
        if (s < S_)
            nzv = fMk ? (((const unsigned char*)maskv)[(size_t)b * S_ + s] != 0)
                      : (((const int*)maskv)[(size_t)b * S_ + s] != 0);
        len += __popcll(__ballot(nzv));
    }
    int last = len - 1;
    int nn = t >> 3, part = t & 7;
    float o_f[16];
    if (fOr) {
        const unsigned short* p = (const unsigned short*)origin + ((size_t)b * N_ + nn) * D_ + part * 16;
#pragma unroll
        for (int j = 0; j < 2; ++j) {
            uint4 u = *(const uint4*)(p + j * 8);
            o_f[j*8+0] = bf2f((unsigned short)(u.x & 0xffff));
            o_f[j*8+1] = bf2f((unsigned short)(u.x >> 16));
            o_f[j*8+2] = bf2f((unsigned short)(u.y & 0xffff));
            o_f[j*8+3] = bf2f((unsigned short)(u.y >> 16));
            o_f[j*8+4] = bf2f((unsigned short)(u.z & 0xffff));
            o_f[j*8+5] = bf2f((unsigned short)(u.z >> 16));
            o_f[j*8+6] = bf2f((unsigned short)(u.w & 0xffff));
            o_f[j*8+7] = bf2f((unsigned short)(u.w >> 16));
        }
    } else {
        const float* p = (const float*)origin + ((size_t)b * N_ + nn) * D_ + part * 16;
#pragma unroll
        for (int j = 0; j < 4; ++j) {
            float4 v = *(const float4*)(p + j * 4);
            o_f[j*4+0] = v.x; o_f[j*4+1] = v.y; o_f[j*4+2] = v.z; o_f[j*4+3] = v.w;
        }
    }

    LBAR();                                                    // S1: sp ready

    // --- softmax by wave 0 (registers + shuffles), writes attn[0..199] ---
    if (wv == 0) {
        int sb = lane * 4;
        float s0 = 0.f, s1 = 0.f, s2 = 0.f, s3 = 0.f;
        if (lane < 50) {
#pragma unroll
            for (int n8 = 0; n8 < 8; ++n8) {
                float4 q = *(const float4*)(sp + n8 * 208 + sb);
                s0 += q.x; s1 += q.y; s2 += q.z; s3 += q.w;
            }
        }
        float m0 = (sb + 0 < len) ? s0 : -INFINITY;
        float m1 = (sb + 1 < len) ? s1 : -INFINITY;
        float m2 = (sb + 2 < len) ? s2 : -INFINITY;
        float m3 = (sb + 3 < len) ? s3 : -INFINITY;
        float m = fmaxf(fmaxf(m0, m1), fmaxf(m2, m3));
#pragma unroll
        for (int off = 32; off; off >>= 1) m = fmaxf(m, __shfl_xor(m, off, 64));
        float e0 = (sb + 0 < len) ? __expf(s0 - m) : 0.f;
        float e1 = (sb + 1 < len) ? __expf(s1 - m) : 0.f;
        float e2 = (sb + 2 < len) ? __expf(s2 - m) : 0.f;
        float e3 = (sb + 3 < len) ? __expf(s3 - m) : 0.f;
        float l = e0 + e1 + e2 + e3;
#pragma unroll
        for (int off = 32; off; off >>= 1) l += __shfl_xor(l, off, 64);
        float inv = 1.0f / l;
        if (lane < 50) {
            float4 av = {e0 * inv, e1 * inv, e2 * inv, e3 * inv};
            *(float4*)(attn + sb) = av;
        }
    }
    LBAR();                                                    // S2: attn ready

    // --- weighted sum: partial[32][128] from Xsh (short8 reads) ---
    {
        int spi = t >> 4;          // 0..31
        int d8 = (t & 15) * 8;     // 0..120
        float a0 = 0.f, a1 = 0.f, a2 = 0.f, a3 = 0.f;
        float a4 = 0.f, a5 = 0.f, a6 = 0.f, a7 = 0.f;
        if (fXs) {
            for (int s = spi; s < S_; s += 32) {
                float ww = attn[s];
                short8 v2 = *(const short8*)(Xsh + s * D_ + (d8 ^ ((s & 7) << 3)));
                a0 = fmaf(ww, bf2f((unsigned short)v2[0]), a0);
                a1 = fmaf(ww, bf2f((unsigned short)v2[1]), a1);
                a2 = fmaf(ww, bf2f((unsigned short)v2[2]), a2);
                a3 = fmaf(ww, bf2f((unsigned short)v2[3]), a3);
                a4 = fmaf(ww, bf2f((unsigned short)v2[4]), a4);
                a5 = fmaf(ww, bf2f((unsigned short)v2[5]), a5);
                a6 = fmaf(ww, bf2f((unsigned short)v2[6]), a6);
                a7 = fmaf(ww, bf2f((unsigned short)v2[7]), a7);
            }
        } else {
            for (int s = spi; s < S_; s += 32) {
                float ww = attn[s];
                const float* p = Xg32 + (size_t)s * D_ + d8;
                float4 u0 = ((const float4*)p)[0], u1 = ((const float4*)p)[1];
                a0 = fmaf(ww, u0.x, a0); a1 = fmaf(ww, u0.y, a1);
                a2 = fmaf(ww, u0.z, a2); a3 = fmaf(ww, u0.w, a3);
                a4 = fmaf(ww, u1.x, a4); a5 = fmaf(ww, u1.y, a5);
                a6 = fmaf(ww, u1.z, a6); a7 = fmaf(ww, u1.w, a7);
            }
        }
        float4 w0 = {a0, a1, a2, a3}, w1 = {a4, a5, a6, a7};
        *(float4*)(ubuf + spi * D_ + d8)     = w0;   // sp is dead now
        *(float4*)(ubuf + spi * D_ + d8 + 4) = w1;
    }
    LBAR();                                                    // S3: partial ready
    {
        int g = t >> 7, d = t & 127;    // 4 groups x 128 d
        float sgp = 0.f;
#pragma unroll
        for (int p = 0; p < 8; ++p) sgp += ubuf[(g * 8 + p) * D_ + d];
        red4[g * D_ + d] = sgp;
    }
    LBAR();                                                    // S4: red4 ready

    // --- epilogue reductions, out write ---
    if (t < D_) {
        float att = red4[t] + red4[D_ + t] + red4[2 * D_ + t] + red4[3 * D_ + t];
        float xl = fXs ? bf2f(Xsh[last * D_ + (t ^ ((last & 7) << 3))])
                       : Xg32[(size_t)last * D_ + t];
        float lv = attn[last] * xl;
        float ov = att - lv;                 // out_vec = attention_output - last_vec
        outv[t] = ov;
        out[(size_t)b * (D_ + 1) + t] = att;
        float r0 = att * xiv;                // inner
        float r1 = lv * lv, r2 = lv * ov, r3 = ov * ov;
#pragma unroll
        for (int off = 32; off; off >>= 1) {
            r0 += __shfl_xor(r0, off, 64);
            r1 += __shfl_xor(r1, off, 64);
            r2 += __shfl_xor(r2, off, 64);
            r3 += __shfl_xor(r3, off, 64);
        }
        if (lane == 0) { red[wv] = r0; red[8 + wv] = r1; red[16 + wv] = r2; red[24 + wv] = r3; }
    }
    LBAR();                                                    // S5: red/outv ready
    float vv = red[24] + red[25];            // ||out_vec||^2 (all threads)
    if (t == 0) {
        out[(size_t)b * (D_ + 1) + D_] = red[0] + red[1];
        float ll = red[8] + red[9], lo = red[16] + red[17];
        float cosv = lo / (sqrtf(fmaxf(ll, 1e-12f)) * sqrtf(fmaxf(vv, 1e-12f)));
        float pl = 0.5f * (1.f - cosv);
        atomicAdd(gsum, log1pf(expf(-pl)));  // global pos-loss sum
    }

    // --- neg losses: thread (nn, part) eighth-dot; pure shuffle reduction ---
    {
        float o_oo = 0.f, o_ov = 0.f;
#pragma unroll
        for (int j = 0; j < 16; ++j) {
            float wv_ = outv[part * 16 + j];
            o_oo = fmaf(o_f[j], o_f[j], o_oo);
            o_ov = fmaf(o_f[j], wv_, o_ov);
        }
        o_oo += __shfl_xor(o_oo, 1, 64); o_ov += __shfl_xor(o_ov, 1, 64);
        o_oo += __shfl_xor(o_oo, 2, 64); o_ov += __shfl_xor(o_ov, 2, 64);
        o_oo += __shfl_xor(o_oo, 4, 64); o_ov += __shfl_xor(o_ov, 4, 64);
        float ns = 0.f;
        if (part == 0) {
            float cosn = o_ov / (sqrtf(fmaxf(o_oo, 1e-12f)) * sqrtf(fmaxf(vv, 1e-12f)));
            float nl = 0.5f * (1.f - cosn);
            ns = log1pf(expf(nl));
        }
        ns += __shfl_xor(ns, 8, 64);
        ns += __shfl_xor(ns, 16, 64);
        ns += __shfl_xor(ns, 32, 64);
        if (lane == 0) red[32 + wv] = ns;
    }
    LBAR();                                                    // S6
    if (t == 0) {
        float nsum = red[32] + red[33] + red[34] + red[35]
                   + red[36] + red[37] + red[38] + red[39];
        neg_sum[b] = nsum;
        __threadfence();
        unsigned int my = atomicAdd(cnt, 1u);
        lastflag = (my == B_ - 1) ? 1 : 0;
    }
    LBAR();                                                    // S7
    if (lastflag) {                                            // last block writes aux row
        __threadfence();
        float gs = *(volatile float*)gsum;
        for (int b2 = t; b2 < B_; b2 += 512)
            out[(size_t)B_ * (D_ + 1) + b2] = gs + neg_sum[b2];
    }
}

extern "C" void kernel_launch(void* const* d_in, const int* in_sizes, int n_in,
                              void* d_out, int out_size, void* d_ws, size_t ws_size,
                              hipStream_t stream) {
    const void* Xs     = d_in[0]; // X_series [B,S,D]
    const void* pos    = d_in[1]; // pos_series [S,D]
    const void* Xitem  = d_in[2]; // X_item [B,D]
    const void* mask   = d_in[3]; // valid_mask [B,S]
    const void* origin = d_in[4]; // origin [B,N,D]
    const void* Wp     = d_in[5]; // [D,H]
    const void* We     = d_in[6]; // [D,H]
    const void* zv     = d_in[7]; // [H]

    unsigned short* WeTf = (unsigned short*)d_ws;                  // 32 KB swizzled
    unsigned short* pbLh = (unsigned short*)((char*)d_ws + 32768); // 13*8*64*4 bf16 = 52 KB
    float* neg_sum  = (float*)((char*)d_ws + 32768 + 53248);       // 1024 f32
    float* gsum     = neg_sum + B_;                                // 1 f32
    unsigned int* cnt = (unsigned int*)(gsum + 1);                 // 1 u32
    float* out = (float*)d_out;                                    // f32 output

    prep_kernel<<<201, 128, 0, stream>>>(We, pos, Wp, WeTf, pbLh, gsum, cnt);
    fused_kernel<<<B_, 512, 0, stream>>>(Xs, Xitem, mask, origin, WeTf, pbLh, zv,
                                         neg_sum, gsum, cnt, out);
}